// Round 11
// baseline (125.776 us; speedup 1.0000x reference)
//
#include <hip/hip_runtime.h>
#include <hip/hip_bf16.h>
#include <stdint.h>

typedef __attribute__((ext_vector_type(8))) short short8;   // 8 bf16 (4 VGPRs) MFMA A/B frag
typedef __attribute__((ext_vector_type(4))) float f32x4;    // MFMA C/D frag

// Fast softplus: max(x,0) + log(1+exp(-|x|)), via v_exp_f32/v_log_f32 HW transcendentals.
__device__ __forceinline__ float softplus_f(float x) {
    float e = __expf(-fabsf(x));
    return fmaxf(x, 0.f) + __logf(1.f + e);
}

// All six input transforms fused into one launch.
// Regions (float4 units): xc 524288 | xf 524288 | Wc 262144 | Wu 262144 | Wut 262144 | U 786432
__global__ void xform_all(const float* __restrict__ xc, const float* __restrict__ xf,
                          const float* __restrict__ Wc_w, const float* __restrict__ Wu_w,
                          const float* __restrict__ Wut_w, const float* __restrict__ raw_U,
                          short* __restrict__ xc_bf, short* __restrict__ xf_bf,
                          short* __restrict__ Wc_bf, short* __restrict__ Wu_bf,
                          short* __restrict__ Wut_bf, short* __restrict__ U_bf)
{
    int j = blockIdx.x * blockDim.x + threadIdx.x;
    const float* src; short* dst; int mode;
    if (j < 524288)                    { src = xc;    dst = xc_bf;  mode = 0; }
    else if ((j -= 524288) < 524288)   { src = xf;    dst = xf_bf;  mode = 0; }
    else if ((j -= 524288) < 262144)   { src = Wc_w;  dst = Wc_bf;  mode = 1; }
    else if ((j -= 262144) < 262144)   { src = Wu_w;  dst = Wu_bf;  mode = 1; }
    else if ((j -= 262144) < 262144)   { src = Wut_w; dst = Wut_bf; mode = 1; }
    else                               { j -= 262144; src = raw_U;  dst = U_bf;  mode = 2; }
    float4 v = reinterpret_cast<const float4*>(src)[j];
    float r[4] = {v.x, v.y, v.z, v.w};
    int base = j << 2;
#pragma unroll
    for (int e = 0; e < 4; ++e) {
        float x = r[e];
        float y = x;
        if (mode == 2) {
            y = softplus_f(x);
        } else if (mode == 1) {
            int col = (base + e) & 255;
            if (col < 8) {
                float s = softplus_f(x);
                y = (col < 4) ? s : -s;
            }
        }
        ((__hip_bfloat16*)dst)[base + e] = __float2bfloat16(y);
    }
}

#define GLOAD16(src, dst)                                                                  \
    __builtin_amdgcn_global_load_lds((const __attribute__((address_space(1))) void*)(src), \
                                     (__attribute__((address_space(3))) void*)(dst), 16, 0, 0)

// inline-asm ds_read_b128: invisible to the compiler's waitcnt pass (no conservative
// vmcnt(0)-before-ds_read drains — the R2-R8 killer). All ordering is explicit.
#define DSREAD(dst, addr, off_lit) \
    asm volatile("ds_read_b128 %0, %1 offset:" #off_lit : "=v"(dst) : "v"(addr))

__device__ __forceinline__ uint32_t lds_addr32(const short* p) {
    return (uint32_t)(uintptr_t)(const __attribute__((address_space(3))) short*)p;
}

// Fused ICNN layer — round-11: R9/R10 skeleton + two stall fixes.
//  - tile 128x128, 4 waves (2x2), per-wave 64x64 (acc[4][4]); grid 64x8=512 = 2 blocks/CU
//  - BK=64, 2 LDS buffer pairs (64KB/block)
//  - per tile t:
//      vmcnt(0)            // stage(t): issued at TOP of t-1, ~2800cyc ago -> free
//      s_barrier
//      stage(t+1)          // moved to TOP (R11 fix 1): full-tile DMA window, no HBM stall.
//                          // WAR-safe: all waves' lgkmcnt(0) for this buffer's reads
//                          // preceded the barrier above.
//      16 asm ds_read_b128
//      lgkmcnt(8) -> 16 MFMA(kk0) -> lgkmcnt(0) -> 16 MFMA(kk1)   // R11 fix 2: counted split
// Step map (HAS_U): t 0-3 xf@Wut^T (relu'd at t=3), 4-7 xc@Wc^T, 8-11 xf@Wu^T, 12-27 z@U^T.
template<bool HAS_U, bool WRITE_F32>
__global__ __launch_bounds__(256, 2)
void icnn_layer_kernel(const short* __restrict__ xc, const short* __restrict__ xf,
                       const short* __restrict__ zin,
                       const short* __restrict__ Wc, const short* __restrict__ Wu,
                       const short* __restrict__ Wut, const short* __restrict__ U,
                       const float* __restrict__ bc, const float* __restrict__ bu,
                       const float* __restrict__ but,
                       __hip_bfloat16* __restrict__ zout, float* __restrict__ fout)
{
    __shared__ short lds_s[4][128 * 64];   // [0],[1]=A bufs; [2],[3]=B bufs; 64KB
    const int t_ = threadIdx.x;            // 0..255
    const int lane = t_ & 63;
    const int wid = t_ >> 6;               // 0..3
    const int wr = wid >> 1, wc = wid & 1; // 2x2 wave grid; 64x64 per wave
    const int l15 = lane & 15, l4 = lane >> 4;
    const int swz = l15 & 7;               // == row&7 for every fragment row this lane reads
    const int brow = blockIdx.x * 128;
    const int bcol = blockIdx.y * 128;

    constexpr int NSTEP = HAS_U ? 28 : 12;

    f32x4 acc[4][4];
#pragma unroll
    for (int m = 0; m < 4; ++m)
#pragma unroll
        for (int n = 0; n < 4; ++n) acc[m][n] = (f32x4){0.f, 0.f, 0.f, 0.f};

    float bt[4];
#pragma unroll
    for (int n = 0; n < 4; ++n) bt[n] = but[bcol + wc * 64 + n * 16 + l15];

    // resolve operands for step s; ld as shift (256 -> 8, 1024 -> 10)
    auto seg = [&](int s, const short*& A, int& lsa, const short*& B, int& lsb, int& k0) {
        if (s < 4)       { A = xf;  lsa = 8;  B = Wut; lsb = 8;  k0 = s * 64; }
        else if (s < 8)  { A = xc;  lsa = 8;  B = Wc;  lsb = 8;  k0 = (s - 4) * 64; }
        else if (s < 12) { A = xf;  lsa = 8;  B = Wu;  lsb = 8;  k0 = (s - 8) * 64; }
        else             { A = zin; lsa = 10; B = U;   lsb = 10; k0 = (s - 12) * 64; }
    };

    // stage tile for step s; LDS dest linear, source column-chunk XOR-swizzled.
    // A 128x64 = 1024 16B-chunks / 256 thr = 4 each; B same. 8 loads/thread.
    auto stage = [&](short* Ad, short* Bd, int s) {
        const short *Ag, *Bg; int lsa, lsb, k0;
        seg(s, Ag, lsa, Bg, lsb, k0);
#pragma unroll
        for (int it = 0; it < 4; ++it) {
            int c = it * 256 + t_;
            int row = c >> 3;                 // 8 chunks per 64-elem row
            int js = (c & 7) ^ (row & 7);     // inverse swizzle on source
            GLOAD16(Ag + (((size_t)(brow + row)) << lsa) + k0 + js * 8, Ad + c * 8);
        }
#pragma unroll
        for (int it = 0; it < 4; ++it) {
            int c = it * 256 + t_;
            int row = c >> 3;
            int js = (c & 7) ^ (row & 7);
            GLOAD16(Bg + (((size_t)(bcol + row)) << lsb) + k0 + js * 8, Bd + c * 8);
        }
    };

    auto tile = [&](const short* As, const short* Bs, short* An, short* Bn, int t) {
        // stage(t) was issued at the TOP of tile t-1 (~one full tile ago) -> wait is free
        asm volatile("s_waitcnt vmcnt(0)" ::: "memory");
        __builtin_amdgcn_s_barrier();

        // R11 fix 1: issue next tile's DMA FIRST -> full-tile window before its vmcnt(0).
        // WAR-safe: every wave's lgkmcnt(0) on An/Bn's reads (tile t-1) preceded the barrier.
        if (t + 1 < NSTEP) stage(An, Bn, t + 1);
        __builtin_amdgcn_sched_barrier(0);

        // fragment base addresses (bytes); row stride 128B, col-chunk XOR-swizzled
        const uint32_t abase = lds_addr32(As) + ((uint32_t)(wr * 64 + l15) << 7);
        const uint32_t bbase = lds_addr32(Bs) + ((uint32_t)(wc * 64 + l15) << 7);
        const uint32_t a0 = abase + (uint32_t)((l4 ^ swz) << 4);
        const uint32_t a1 = abase + (uint32_t)(((4 + l4) ^ swz) << 4);
        const uint32_t b0 = bbase + (uint32_t)((l4 ^ swz) << 4);
        const uint32_t b1 = bbase + (uint32_t)(((4 + l4) ^ swz) << 4);

        short8 a[2][4], b[2][4];
        // kk0 group first (8 reads), then kk1 group (8 reads) — order matters for lgkmcnt(8)
        DSREAD(a[0][0], a0, 0);    DSREAD(a[0][1], a0, 2048);
        DSREAD(a[0][2], a0, 4096); DSREAD(a[0][3], a0, 6144);
        DSREAD(b[0][0], b0, 0);    DSREAD(b[0][1], b0, 2048);
        DSREAD(b[0][2], b0, 4096); DSREAD(b[0][3], b0, 6144);
        DSREAD(a[1][0], a1, 0);    DSREAD(a[1][1], a1, 2048);
        DSREAD(a[1][2], a1, 4096); DSREAD(a[1][3], a1, 6144);
        DSREAD(b[1][0], b1, 0);    DSREAD(b[1][1], b1, 2048);
        DSREAD(b[1][2], b1, 4096); DSREAD(b[1][3], b1, 6144);

        // R11 fix 2: counted lgkm split — MFMA(kk0) runs under kk1's read latency
        asm volatile("s_waitcnt lgkmcnt(8)" ::: "memory");
        __builtin_amdgcn_sched_barrier(0);   // rule 18
        __builtin_amdgcn_s_setprio(1);
#pragma unroll
        for (int m = 0; m < 4; ++m)
#pragma unroll
            for (int n = 0; n < 4; ++n)
                acc[m][n] = __builtin_amdgcn_mfma_f32_16x16x32_bf16(a[0][m], b[0][n], acc[m][n], 0, 0, 0);
        asm volatile("s_waitcnt lgkmcnt(0)" ::: "memory");
        __builtin_amdgcn_sched_barrier(0);
#pragma unroll
        for (int m = 0; m < 4; ++m)
#pragma unroll
            for (int n = 0; n < 4; ++n)
                acc[m][n] = __builtin_amdgcn_mfma_f32_16x16x32_bf16(a[1][m], b[1][n], acc[m][n], 0, 0, 0);
        __builtin_amdgcn_s_setprio(0);

        if (t == 3) {
            // u = relu(xf@Wut^T + but); MFMA accumulates the remaining paths on top
#pragma unroll
            for (int n = 0; n < 4; ++n)
#pragma unroll
                for (int m = 0; m < 4; ++m)
#pragma unroll
                    for (int v = 0; v < 4; ++v)
                        acc[m][n][v] = fmaxf(acc[m][n][v] + bt[n], 0.f);
        }
    };

    // ---- prologue ----
    stage(lds_s[0], lds_s[2], 0);

    // ---- main loop: buffer identity compile-time via x2 unroll (NSTEP even) ----
    for (int i = 0; i < NSTEP / 2; ++i) {
        tile(lds_s[0], lds_s[2], lds_s[1], lds_s[3], 2 * i);
        tile(lds_s[1], lds_s[3], lds_s[0], lds_s[2], 2 * i + 1);
    }

    // ---- epilogue: + (bc + bu), relu, store ----
    float bb[4];
#pragma unroll
    for (int n = 0; n < 4; ++n) {
        int col = bcol + wc * 64 + n * 16 + l15;
        bb[n] = bc[col] + bu[col];
    }

    if constexpr (WRITE_F32) {
        // f32: 16 consecutive lanes cover one full 64B line -> direct store
#pragma unroll
        for (int n = 0; n < 4; ++n) {
            int col = bcol + wc * 64 + n * 16 + l15;
#pragma unroll
            for (int m = 0; m < 4; ++m) {
                int row = brow + wr * 64 + m * 16 + l4 * 4;
#pragma unroll
                for (int v = 0; v < 4; ++v)
                    fout[(size_t)(row + v) * 1024 + col] = fmaxf(acc[m][n][v] + bb[n], 0.f);
            }
        }
    } else {
        // bf16: bounce via LDS (64KB = 128x128 f32) for full-line 64B global writes
        __syncthreads();   // all DMA drained (last tile waited vmcnt(0)); all frag reads done
        float* fs = (float*)&lds_s[0][0];
#pragma unroll
        for (int n = 0; n < 4; ++n) {
            int col = wc * 64 + n * 16 + l15;
#pragma unroll
            for (int m = 0; m < 4; ++m) {
                int row = wr * 64 + m * 16 + l4 * 4;
#pragma unroll
                for (int v = 0; v < 4; ++v)
                    fs[(row + v) * 128 + col] = fmaxf(acc[m][n][v] + bb[n], 0.f);
            }
        }
        __syncthreads();
        const int rrow = t_ >> 5;          // 0..7
        const int rcol = (t_ & 31) * 4;    // 0..124
#pragma unroll
        for (int p = 0; p < 16; ++p) {
            int row = p * 8 + rrow;
            float4 v4 = *(const float4*)&fs[row * 128 + rcol];
            ushort4 o;
            o.x = __bfloat16_as_ushort(__float2bfloat16(v4.x));
            o.y = __bfloat16_as_ushort(__float2bfloat16(v4.y));
            o.z = __bfloat16_as_ushort(__float2bfloat16(v4.z));
            o.w = __bfloat16_as_ushort(__float2bfloat16(v4.w));
            *(ushort4*)&zout[(size_t)(brow + row) * 1024 + bcol + rcol] = o;
        }
    }
}

extern "C" void kernel_launch(void* const* d_in, const int* in_sizes, int n_in,
                              void* d_out, int out_size, void* d_ws, size_t ws_size,
                              hipStream_t stream)
{
    const float* xc    = (const float*)d_in[0];
    const float* xf    = (const float*)d_in[1];
    const float* Wc_w  = (const float*)d_in[2];
    const float* Wc_b  = (const float*)d_in[3];
    const float* Wu_w  = (const float*)d_in[4];
    const float* Wu_b  = (const float*)d_in[5];
    const float* Wut_w = (const float*)d_in[6];
    const float* Wut_b = (const float*)d_in[7];
    const float* raw_U = (const float*)d_in[8];

    // workspace layout (bf16 buffers), ~36 MB total
    short* p = (short*)d_ws;
    short* xc_bf  = p; p += 8192 * 256;
    short* xf_bf  = p; p += 8192 * 256;
    short* Wc_bf  = p; p += 4 * 1024 * 256;
    short* Wu_bf  = p; p += 4 * 1024 * 256;
    short* Wut_bf = p; p += 4 * 1024 * 256;
    short* U_bf   = p; p += 3 * 1024 * 1024;
    short* z_a    = p; p += 8192 * 1024;
    // z_b lives in d_out (bf16 scratch); layer 3 fully overwrites d_out with fp32 result.
    short* z_b = (short*)d_out;

    xform_all<<<dim3(10240), dim3(256), 0, stream>>>(
        xc, xf, Wc_w, Wu_w, Wut_w, raw_U,
        xc_bf, xf_bf, Wc_bf, Wu_bf, Wut_bf, U_bf);

    dim3 tb(256);
    dim3 grid(8192 / 128, 1024 / 128);   // 64 x 8 = 512 blocks = 2/CU
    const int WS = 1024 * 256;
    const int US = 1024 * 1024;

    // layer 0 (no recurrence) -> z_a
    icnn_layer_kernel<false, false><<<grid, tb, 0, stream>>>(
        xc_bf, xf_bf, nullptr, Wc_bf, Wu_bf, Wut_bf, nullptr,
        Wc_b, Wu_b, Wut_b, (__hip_bfloat16*)z_a, nullptr);
    // layer 1 -> z_b (in d_out)
    icnn_layer_kernel<true, false><<<grid, tb, 0, stream>>>(
        xc_bf, xf_bf, z_a, Wc_bf + WS, Wu_bf + WS, Wut_bf + WS, U_bf,
        Wc_b + 1024, Wu_b + 1024, Wut_b + 1024, (__hip_bfloat16*)z_b, nullptr);
    // layer 2 -> z_a
    icnn_layer_kernel<true, false><<<grid, tb, 0, stream>>>(
        xc_bf, xf_bf, z_b, Wc_bf + 2 * WS, Wu_bf + 2 * WS, Wut_bf + 2 * WS, U_bf + US,
        Wc_b + 2048, Wu_b + 2048, Wut_b + 2048, (__hip_bfloat16*)z_a, nullptr);
    // layer 3 -> fp32 d_out
    icnn_layer_kernel<true, true><<<grid, tb, 0, stream>>>(
        xc_bf, xf_bf, z_a, Wc_bf + 3 * WS, Wu_bf + 3 * WS, Wut_bf + 3 * WS, U_bf + 2 * US,
        Wc_b + 3072, Wu_b + 3072, Wut_b + 3072, nullptr, (float*)d_out);
}